// Round 12
// baseline (11990.428 us; speedup 1.0000x reference)
//
#include <hip/hip_runtime.h>
#include <hip/hip_bf16.h>

#define T_LEN 2048
#define N_IN 256
#define N_H 512
#define N_B 64
#define FLAG_STRIDE 32  // ints -> 128B per flag line

typedef float f32x4 __attribute__((ext_vector_type(4)));
typedef __bf16 bf16x8 __attribute__((ext_vector_type(8)));

__device__ __forceinline__ unsigned short f2bf(float f) {
  union { float f; unsigned int i; } x; x.f = f;
  unsigned int r = x.i + 0x7fffu + ((x.i >> 16) & 1u);  // RNE
  return (unsigned short)(r >> 16);
}
__device__ __forceinline__ float sigm(float x) { return 1.0f / (1.0f + __expf(-x)); }
__device__ __forceinline__ float tanh_(float x) {
  float a = fabsf(x);
  float e = __expf(2.0f * a);
  float r = 1.0f - 2.0f / (e + 1.0f);
  return copysignf(r, x);
}
// convert 8 consecutive f32 -> bf16x8 (RNE)
__device__ __forceinline__ bf16x8 cvt8(const float* __restrict__ p) {
  f32x4 a = *(const f32x4*)(const void*)p;
  f32x4 b = *(const f32x4*)(const void*)(p + 4);
  union { bf16x8 v; unsigned short u[8]; } r;
  #pragma unroll
  for (int j = 0; j < 4; ++j) { r.u[j] = f2bf(a[j]); r.u[j + 4] = f2bf(b[j]); }
  return r.v;
}

// ws layout: [0, 8192) flags (64 x FLAG_STRIDE ints)
//            [8192, 8192+131072) hbuf u16: [group 4][buf 2][producer 16][row 16][col 32]
__global__ void lstm_init(int* __restrict__ ws) {
  int i = blockIdx.x * 256 + threadIdx.x;  // grid 136 covers 8192B + 128KB
  if (i < (8192 + 2 * N_B * N_H * 2) / 4) ws[i] = 0;
}

// 64 WGs x 128 threads. Group g = blockIdx&3 owns batch rows 16g..16g+15 (independent
// recurrence domain). Member m = blockIdx>>2 owns hidden cols 32m..32m+31 (3 gates in LDS).
__global__ __launch_bounds__(128, 1) void lstm_persist(
    const float* __restrict__ X,     // [64, 2048, 256] f32
    const float* __restrict__ HID,   // [1, 512] f32 (passthrough)
    const float* __restrict__ Wi, const float* __restrict__ bi,
    const float* __restrict__ Wg, const float* __restrict__ bg,
    const float* __restrict__ Wo, const float* __restrict__ bo,
    const float* __restrict__ Wout, const float* __restrict__ bout,
    float* __restrict__ out,                  // f32: [64*256] + [512]
    unsigned short* __restrict__ hbuf,        // see layout above
    int* __restrict__ flags)                  // 64 x FLAG_STRIDE ints
{
  extern __shared__ unsigned short ldsw[];  // 96 rows x 768 k swizzled (147456 B) + 1024 B scratch
  unsigned short* ldsh = ldsw + 96 * 768;   // [16 rows][32 cols] u16 (holds own h slice)
  const int tid = threadIdx.x;
  const int b = blockIdx.x;
  const int g = b & 3;             // group (batch split)
  const int m = b >> 2;            // member: hidden col slice
  const int lane = tid & 63;
  const int wave = tid >> 6;       // 0..1 -> col-tile within WG
  const int q = lane >> 4;         // 0..3
  const int c = lane & 15;
  const int jb = m * 32;           // WG's hidden col base
  const int wcol = wave * 16;      // col-tile offset within WG

  // hidden passthrough output (independent of recurrence), f32
  if (b == 0) {
    for (int i = tid; i < N_H; i += 128) out[N_B * N_IN + i] = HID[i];
  }

  // ---- stage weight slice into LDS (f32 -> bf16), transposed: Wt[r][k], r = gate*32 + (col-jb) ----
  for (int idx = tid; idx < 96 * 768; idx += 128) {
    int k = idx / 96;
    int r = idx - k * 96;
    int g3 = r >> 5;
    int cc = r & 31;
    const float* W = (g3 == 0) ? Wi : ((g3 == 1) ? Wg : Wo);
    unsigned short v = f2bf(W[k * N_H + jb + cc]);
    int byte = (r * 1536 + k * 2) ^ ((r & 7) << 4);  // XOR swizzle (G4)
    *(unsigned short*)((char*)ldsw + byte) = v;
  }
  // zero own-slice scratch (h_0 = 0)
  for (int i = tid; i < 512; i += 128) ldsh[i] = 0;
  __syncthreads();

  // B-fragment read: lane holds Wt[gg*32 + wcol + c][kt*32 + q*8 + j], j=0..7 (16B contiguous)
  auto ldb = [&](int gg, int kt) -> bf16x8 {
    int r = gg * 32 + wcol + c;
    int byte = (r * 1536 + kt * 64 + q * 16) ^ ((r & 7) << 4);
    return *(const bf16x8*)((const char*)ldsw + byte);
  };

  const float Bi = bi[jb + wcol + c];
  const float Bg = bg[jb + wcol + c];
  const float Bo = bo[jb + wcol + c];

  const float* xrow = X + (size_t)(g * 16 + c) * (T_LEN * N_IN);  // A row c = group row c

  // group h buffers (u16 units): base = g*16384 + buf*8192; slice layout [producer][row16][col32]
  unsigned short* gh0 = hbuf + g * 16384;
  // read fragment (kk, row c, kslot q): u64 idx = kk*128 + c*8 + q*2 (+0,+1)
  const int roff64 = c * 8 + q * 2;

  #pragma unroll 1
  for (int t = 0; t < T_LEN; ++t) {
    f32x4 ai = {0.f, 0.f, 0.f, 0.f};
    f32x4 ag = {0.f, 0.f, 0.f, 0.f};
    f32x4 ao = {0.f, 0.f, 0.f, 0.f};

    // ---- x-part GEMM (independent of h -> before any waiting) ----
    const float* xp = xrow + (size_t)t * N_IN + q * 8;
    #pragma unroll
    for (int kk = 0; kk < 8; ++kk) {
      bf16x8 a = cvt8(xp + kk * 32);
      ai = __builtin_amdgcn_mfma_f32_16x16x32_bf16(a, ldb(0, kk), ai, 0, 0, 0);
      ag = __builtin_amdgcn_mfma_f32_16x16x32_bf16(a, ldb(1, kk), ag, 0, 0, 0);
      ao = __builtin_amdgcn_mfma_f32_16x16x32_bf16(a, ldb(2, kk), ao, 0, 0, 0);
    }

    // ---- h-part: own slice from LDS scratch (left over from step t-1; zeros at t=0) ----
    {
      bf16x8 a = *(const bf16x8*)(const void*)(ldsh + c * 32 + q * 8);
      ai = __builtin_amdgcn_mfma_f32_16x16x32_bf16(a, ldb(0, m + 8), ai, 0, 0, 0);
      ag = __builtin_amdgcn_mfma_f32_16x16x32_bf16(a, ldb(1, m + 8), ag, 0, 0, 0);
      ao = __builtin_amdgcn_mfma_f32_16x16x32_bf16(a, ldb(2, m + 8), ao, 0, 0, 0);
    }

    // ---- remote slices in ARRIVAL ORDER (per-producer flags; 1-deep load/MFMA pipeline) ----
    const unsigned long long* hb64 =
        (const unsigned long long*)(gh0 + (size_t)(t & 1) * 8192);
    unsigned done = 1u << m;
    int pend = -1;
    unsigned long long p0 = 0, p1 = 0;
    while (done != 0xFFFFu) {
      int fl = 0;
      if (lane < 16)
        fl = __hip_atomic_load(&flags[(g * 16 + lane) * FLAG_STRIDE],
                               __ATOMIC_RELAXED, __HIP_MEMORY_SCOPE_AGENT);
      unsigned long long bal = __ballot(fl >= t);
      unsigned ready = (unsigned)bal & 0xFFFFu & ~done;
      while (ready) {
        int kk = __ffs(ready) - 1;
        ready &= ready - 1;
        done |= 1u << kk;
        unsigned long long q0 = __hip_atomic_load(hb64 + kk * 128 + roff64,
                                                  __ATOMIC_RELAXED, __HIP_MEMORY_SCOPE_AGENT);
        unsigned long long q1 = __hip_atomic_load(hb64 + kk * 128 + roff64 + 1,
                                                  __ATOMIC_RELAXED, __HIP_MEMORY_SCOPE_AGENT);
        if (pend >= 0) {  // MFMA previous slice while q0/q1 in flight
          union { unsigned long long u[2]; bf16x8 v; } a;
          a.u[0] = p0; a.u[1] = p1;
          ai = __builtin_amdgcn_mfma_f32_16x16x32_bf16(a.v, ldb(0, pend + 8), ai, 0, 0, 0);
          ag = __builtin_amdgcn_mfma_f32_16x16x32_bf16(a.v, ldb(1, pend + 8), ag, 0, 0, 0);
          ao = __builtin_amdgcn_mfma_f32_16x16x32_bf16(a.v, ldb(2, pend + 8), ao, 0, 0, 0);
        }
        p0 = q0; p1 = q1; pend = kk;
      }
    }
    if (pend >= 0) {  // drain pipeline
      union { unsigned long long u[2]; bf16x8 v; } a;
      a.u[0] = p0; a.u[1] = p1;
      ai = __builtin_amdgcn_mfma_f32_16x16x32_bf16(a.v, ldb(0, pend + 8), ai, 0, 0, 0);
      ag = __builtin_amdgcn_mfma_f32_16x16x32_bf16(a.v, ldb(1, pend + 8), ag, 0, 0, 0);
      ao = __builtin_amdgcn_mfma_f32_16x16x32_bf16(a.v, ldb(2, pend + 8), ao, 0, 0, 0);
    }

    // ---- nonlinearity -> LDS transpose -> coalesced coherent u64 stores ----
    __syncthreads();  // both waves done reading ldsh (own slice) before overwrite
    #pragma unroll
    for (int j = 0; j < 4; ++j) {
      float iv = sigm(ai[j] + Bi);
      float gv = tanh_(ag[j] + Bg);
      float ov = sigm(ao[j] + Bo);
      float h = ov * tanh_(iv * gv);
      int row = q * 4 + j;  // D layout: col=lane&15, row=q*4+j (m89)
      ldsh[row * 32 + wcol + c] = f2bf(h);
    }
    __syncthreads();  // LDS visibility across both waves
    {
      unsigned long long v = *(const unsigned long long*)(const void*)(ldsh + tid * 4);
      unsigned long long* hn64 =
          (unsigned long long*)(gh0 + (size_t)((t + 1) & 1) * 8192 + m * 512);
      __hip_atomic_store(&hn64[tid], v, __ATOMIC_RELAXED, __HIP_MEMORY_SCOPE_AGENT);
    }
    __syncthreads();  // vmcnt(0) drain: every thread's sc-store acked
    if (tid == 0)
      __hip_atomic_store(&flags[(g * 16 + m) * FLAG_STRIDE], t + 1,
                         __ATOMIC_RELEASE, __HIP_MEMORY_SCOPE_AGENT);
  }

  // ---- epilogue: out[group rows][16 cols] = h_T @ W_out + b_out ; h_T in buf 0 (T even) ----
  {
    if (wave == 0) {
      for (;;) {
        int v = __hip_atomic_load(&flags[(g * 16 + (lane & 15)) * FLAG_STRIDE],
                                  __ATOMIC_RELAXED, __HIP_MEMORY_SCOPE_AGENT);
        if (__all(v >= T_LEN)) break;
      }
    }
    __syncthreads();

    if (wave == 0) {
      const unsigned long long* hb64 = (const unsigned long long*)gh0 + roff64;
      f32x4 acc = {0.f, 0.f, 0.f, 0.f};
      #pragma unroll 4
      for (int kk = 0; kk < 16; ++kk) {
        union { unsigned long long u[2]; bf16x8 v; } a;
        a.u[0] = __hip_atomic_load(hb64 + kk * 128,     __ATOMIC_RELAXED, __HIP_MEMORY_SCOPE_AGENT);
        a.u[1] = __hip_atomic_load(hb64 + kk * 128 + 1, __ATOMIC_RELAXED, __HIP_MEMORY_SCOPE_AGENT);
        union { bf16x8 v; unsigned short u[8]; } bb;
        #pragma unroll
        for (int j = 0; j < 8; ++j)
          bb.u[j] = f2bf(Wout[(size_t)(kk * 32 + q * 8 + j) * N_IN + m * 16 + c]);
        acc = __builtin_amdgcn_mfma_f32_16x16x32_bf16(a.v, bb.v, acc, 0, 0, 0);
      }
      const float Bb = bout[m * 16 + c];
      #pragma unroll
      for (int j = 0; j < 4; ++j) {
        int row = q * 4 + j;  // group row
        out[(g * 16 + row) * N_IN + m * 16 + c] = acc[j] + Bb;  // f32 store
      }
    }
  }
}

extern "C" void kernel_launch(void* const* d_in, const int* in_sizes, int n_in,
                              void* d_out, int out_size, void* d_ws, size_t ws_size,
                              hipStream_t stream) {
  const float* X    = (const float*)d_in[0];
  const float* HID  = (const float*)d_in[1];
  const float* Wi   = (const float*)d_in[2];
  const float* bi   = (const float*)d_in[3];
  const float* Wg   = (const float*)d_in[4];
  const float* bg   = (const float*)d_in[5];
  const float* Wo   = (const float*)d_in[6];
  const float* bo   = (const float*)d_in[7];
  const float* Wout = (const float*)d_in[8];
  const float* bout = (const float*)d_in[9];

  int* flags = (int*)d_ws;
  unsigned short* hbuf = (unsigned short*)((char*)d_ws + 8192);

  lstm_init<<<dim3(136), dim3(256), 0, stream>>>((int*)d_ws);
  lstm_persist<<<dim3(64), dim3(128), 96 * 768 * 2 + 1024, stream>>>(
      X, HID, Wi, bi, Wg, bg, Wo, bo, Wout, bout,
      (float*)d_out, hbuf, flags);
}

// Round 15
// 9909.641 us; speedup vs baseline: 1.2100x; 1.2100x over previous
//
#include <hip/hip_runtime.h>
#include <hip/hip_bf16.h>

#define T_LEN 2048
#define N_IN 256
#define N_H 512
#define N_B 64
#define FLAG_STRIDE 32  // ints -> 128B per flag line

typedef float f32x4 __attribute__((ext_vector_type(4)));
typedef __bf16 bf16x8 __attribute__((ext_vector_type(8)));

__device__ __forceinline__ unsigned short f2bf(float f) {
  union { float f; unsigned int i; } x; x.f = f;
  unsigned int r = x.i + 0x7fffu + ((x.i >> 16) & 1u);  // RNE
  return (unsigned short)(r >> 16);
}
__device__ __forceinline__ float sigm(float x) { return 1.0f / (1.0f + __expf(-x)); }
__device__ __forceinline__ float tanh_(float x) {
  float a = fabsf(x);
  float e = __expf(2.0f * a);
  float r = 1.0f - 2.0f / (e + 1.0f);
  return copysignf(r, x);
}
// convert 8 consecutive f32 -> bf16x8 (RNE)
__device__ __forceinline__ bf16x8 cvt8(const float* __restrict__ p) {
  f32x4 a = *(const f32x4*)(const void*)p;
  f32x4 b = *(const f32x4*)(const void*)(p + 4);
  union { bf16x8 v; unsigned short u[8]; } r;
  #pragma unroll
  for (int j = 0; j < 4; ++j) { r.u[j] = f2bf(a[j]); r.u[j + 4] = f2bf(b[j]); }
  return r.v;
}

// ws layout: [0, 16384) half-flags: 128 entries (group*32 + member*2 + wave) x FLAG_STRIDE ints
//            [16384, 16384+131072) hbuf u16: [group 4][buf 2][slice 16][whalf 2][brow 16][hcol 16]
__global__ void lstm_init(int* __restrict__ ws) {
  int i = blockIdx.x * 256 + threadIdx.x;  // grid 144 -> 36864 ints = 16384B + 128KB
  if (i < (16384 + 2 * N_B * N_H * 2) / 4) ws[i] = 0;
}

// 64 WGs x 128 threads. Group g = bid&3 owns batch rows 16g..16g+15 (independent
// recurrence). Member m = bid>>2 owns hidden cols 32m..32m+31; wave w owns 16 of them.
// Waves fully decoupled: no __syncthreads in the main loop.
__global__ __launch_bounds__(128, 1) void lstm_persist(
    const float* __restrict__ X,     // [64, 2048, 256] f32
    const float* __restrict__ HID,   // [1, 512] f32 (passthrough)
    const float* __restrict__ Wi, const float* __restrict__ bi,
    const float* __restrict__ Wg, const float* __restrict__ bg,
    const float* __restrict__ Wo, const float* __restrict__ bo,
    const float* __restrict__ Wout, const float* __restrict__ bout,
    float* __restrict__ out,                  // f32: [64*256] + [512]
    unsigned short* __restrict__ hbuf,
    int* __restrict__ flags)
{
  extern __shared__ unsigned short ldsw[];  // 96*768 swizzled weights + 768 u16 scratch
  unsigned short* ldsh = ldsw + 96 * 768;   // per-wave [16 brow][24 pad] u16 (wave*384)
  const int tid = threadIdx.x;
  const int b = blockIdx.x;
  const int g = b & 3;             // group (batch split)
  const int m = b >> 2;            // member: hidden col slice
  const int lane = tid & 63;
  const int wave = tid >> 6;       // 0..1 -> col-half within member
  const int q = lane >> 4;         // 0..3
  const int c = lane & 15;
  const int jb = m * 32;
  const int wcol = wave * 16;

  // hidden passthrough output (independent of recurrence), f32
  if (b == 0) {
    for (int i = tid; i < N_H; i += 128) out[N_B * N_IN + i] = HID[i];
  }

  // ---- stage weight slice into LDS (f32 -> bf16), transposed: Wt[r][k], r = gate*32 + (col-jb) ----
  for (int idx = tid; idx < 96 * 768; idx += 128) {
    int k = idx / 96, r = idx - k * 96;
    int g3 = r >> 5, cc = r & 31;
    const float* W = (g3 == 0) ? Wi : ((g3 == 1) ? Wg : Wo);
    unsigned short v = f2bf(W[k * N_H + jb + cc]);
    int byte = (r * 1536 + k * 2) ^ ((r & 7) << 4);  // XOR swizzle (G4)
    *(unsigned short*)((char*)ldsw + byte) = v;
  }
  __syncthreads();  // the only block-wide barrier (weights read-only afterwards)

  // B-fragment read: lane holds Wt[gg*32 + wcol + c][kt*32 + q*8 + j], j=0..7 (16B contiguous)
  auto ldb = [&](int gg, int kt) -> bf16x8 {
    int r = gg * 32 + wcol + c;
    int byte = (r * 1536 + kt * 64 + q * 16) ^ ((r & 7) << 4);
    return *(const bf16x8*)((const char*)ldsw + byte);
  };

  const float Bi = bi[jb + wcol + c];
  const float Bg = bg[jb + wcol + c];
  const float Bo = bo[jb + wcol + c];

  const float* xrow = X + (size_t)(g * 16 + c) * (T_LEN * N_IN);  // A row = group row c

  // group h base (u16): g*16384; parity offset 8192.
  // slice layout (u16 within slice of 512): whalf*256 + brow*16 + hcol(0..15)
  unsigned short* gh0 = hbuf + g * 16384;
  // reader fragment (brow c, k = q*8+j): u64 idx = slice*128 + (q>>1)*64 + c*4 + (q&1)*2 (+1)
  const int roff64 = (q >> 1) * 64 + c * 4 + (q & 1) * 2;
  // scratch: write (brow=4q+j, hcol=c) at wave*384 + (4q+j)*24 + c
  // readback lane: (brow=lane>>2, hcolgrp=lane&3) -> u64 at u16 idx wave*384 + (lane>>2)*24 + (lane&3)*4
  const int swr = wave * 384;
  const int srb = wave * 384 + (lane >> 2) * 24 + (lane & 3) * 4;
  const int hflag = (g * 32 + m * 2 + wave) * FLAG_STRIDE;   // this wave's flag
  const int pflag = (g * 32 + (lane & 31)) * FLAG_STRIDE;    // poll set (32 half-flags)

  #pragma unroll 1
  for (int t = 0; t < T_LEN; ++t) {
    f32x4 ai = {0.f, 0.f, 0.f, 0.f};
    f32x4 ag = {0.f, 0.f, 0.f, 0.f};
    f32x4 ao = {0.f, 0.f, 0.f, 0.f};

    // ---- x-part GEMM (independent of h -> hides under predecessors' publish) ----
    const float* xp = xrow + (size_t)t * N_IN + q * 8;
    #pragma unroll
    for (int kk = 0; kk < 8; ++kk) {
      bf16x8 a = cvt8(xp + kk * 32);
      ai = __builtin_amdgcn_mfma_f32_16x16x32_bf16(a, ldb(0, kk), ai, 0, 0, 0);
      ag = __builtin_amdgcn_mfma_f32_16x16x32_bf16(a, ldb(1, kk), ag, 0, 0, 0);
      ao = __builtin_amdgcn_mfma_f32_16x16x32_bf16(a, ldb(2, kk), ao, 0, 0, 0);
    }

    // ---- every wave polls all 32 half-flags itself (no barrier) ----
    for (;;) {
      int v = __hip_atomic_load(&flags[pflag], __ATOMIC_RELAXED, __HIP_MEMORY_SCOPE_AGENT);
      if (__all(v >= t)) break;
    }

    // ---- h-part GEMM: batched coherent u64 loads of all 16 slices ----
    const unsigned long long* hb64 =
        (const unsigned long long*)(gh0 + (size_t)(t & 1) * 8192);
    unsigned long long hreg[32];
    #pragma unroll
    for (int kk = 0; kk < 16; ++kk) {
      hreg[2 * kk]     = __hip_atomic_load(hb64 + kk * 128 + roff64,
                                           __ATOMIC_RELAXED, __HIP_MEMORY_SCOPE_AGENT);
      hreg[2 * kk + 1] = __hip_atomic_load(hb64 + kk * 128 + roff64 + 1,
                                           __ATOMIC_RELAXED, __HIP_MEMORY_SCOPE_AGENT);
    }
    #pragma unroll
    for (int kk = 0; kk < 16; ++kk) {
      union { unsigned long long u[2]; bf16x8 v; } a;
      a.u[0] = hreg[2 * kk]; a.u[1] = hreg[2 * kk + 1];
      ai = __builtin_amdgcn_mfma_f32_16x16x32_bf16(a.v, ldb(0, kk + 8), ai, 0, 0, 0);
      ag = __builtin_amdgcn_mfma_f32_16x16x32_bf16(a.v, ldb(1, kk + 8), ag, 0, 0, 0);
      ao = __builtin_amdgcn_mfma_f32_16x16x32_bf16(a.v, ldb(2, kk + 8), ao, 0, 0, 0);
    }

    // ---- nonlinearity -> wave-private padded scratch -> coalesced u64 store ----
    #pragma unroll
    for (int j = 0; j < 4; ++j) {
      float iv = sigm(ai[j] + Bi);
      float gv = tanh_(ag[j] + Bg);
      float ov = sigm(ao[j] + Bo);
      float h = ov * tanh_(iv * gv);
      ldsh[swr + (q * 4 + j) * 24 + c] = f2bf(h);  // D: col=lane&15, row=q*4+j (m89)
    }
    // ORDERING FIX (r14 bug): the u64 readback type-puns the u16 scratch —
    // TBAA lets the compiler hoist it above the writes. Fence the compiler AND
    // wait for this wave's own LDS writes before reading them back.
    asm volatile("s_waitcnt lgkmcnt(0)" ::: "memory");
    {
      unsigned long long v64;
      __builtin_memcpy(&v64, (const void*)(ldsh + srb), 8);
      unsigned long long* hn =
          (unsigned long long*)(gh0 + (size_t)((t + 1) & 1) * 8192) + m * 128 + tid;
      __hip_atomic_store(hn, v64, __ATOMIC_RELAXED, __HIP_MEMORY_SCOPE_AGENT);
    }
    // per-wave release flag: orders this wave's h stores before the flag
    if (lane == 0)
      __hip_atomic_store(&flags[hflag], t + 1,
                         __ATOMIC_RELEASE, __HIP_MEMORY_SCOPE_AGENT);
  }

  // ---- epilogue: out = h_T @ W_out + b_out ; h_T in parity 0 (T even) ----
  if (wave == 0) {
    for (;;) {
      int v = __hip_atomic_load(&flags[pflag], __ATOMIC_RELAXED, __HIP_MEMORY_SCOPE_AGENT);
      if (__all(v >= T_LEN)) break;
    }
    const unsigned long long* hb64 = (const unsigned long long*)gh0;
    f32x4 acc = {0.f, 0.f, 0.f, 0.f};
    #pragma unroll 4
    for (int kk = 0; kk < 16; ++kk) {
      union { unsigned long long u[2]; bf16x8 v; } a;
      a.u[0] = __hip_atomic_load(hb64 + kk * 128 + roff64,
                                 __ATOMIC_RELAXED, __HIP_MEMORY_SCOPE_AGENT);
      a.u[1] = __hip_atomic_load(hb64 + kk * 128 + roff64 + 1,
                                 __ATOMIC_RELAXED, __HIP_MEMORY_SCOPE_AGENT);
      union { bf16x8 v; unsigned short u[8]; } bb;
      #pragma unroll
      for (int j = 0; j < 8; ++j)
        bb.u[j] = f2bf(Wout[(size_t)(kk * 32 + q * 8 + j) * N_IN + m * 16 + c]);
      acc = __builtin_amdgcn_mfma_f32_16x16x32_bf16(a.v, bb.v, acc, 0, 0, 0);
    }
    const float Bb = bout[m * 16 + c];
    #pragma unroll
    for (int j = 0; j < 4; ++j) {
      int row = q * 4 + j;  // group row
      out[(g * 16 + row) * N_IN + m * 16 + c] = acc[j] + Bb;  // f32 store
    }
  }
}

extern "C" void kernel_launch(void* const* d_in, const int* in_sizes, int n_in,
                              void* d_out, int out_size, void* d_ws, size_t ws_size,
                              hipStream_t stream) {
  const float* X    = (const float*)d_in[0];
  const float* HID  = (const float*)d_in[1];
  const float* Wi   = (const float*)d_in[2];
  const float* bi   = (const float*)d_in[3];
  const float* Wg   = (const float*)d_in[4];
  const float* bg   = (const float*)d_in[5];
  const float* Wo   = (const float*)d_in[6];
  const float* bo   = (const float*)d_in[7];
  const float* Wout = (const float*)d_in[8];
  const float* bout = (const float*)d_in[9];

  int* flags = (int*)d_ws;
  unsigned short* hbuf = (unsigned short*)((char*)d_ws + 16384);

  lstm_init<<<dim3(144), dim3(256), 0, stream>>>((int*)d_ws);
  lstm_persist<<<dim3(64), dim3(128), 96 * 768 * 2 + 1536, stream>>>(
      X, HID, Wi, bi, Wg, bg, Wo, bo, Wout, bout,
      (float*)d_out, hbuf, flags);
}

// Round 16
// 8929.103 us; speedup vs baseline: 1.3428x; 1.1098x over previous
//
#include <hip/hip_runtime.h>
#include <hip/hip_bf16.h>

#define T_LEN 2048
#define N_IN 256
#define N_H 512
#define N_B 64
#define FLAG_STRIDE 32  // ints -> 128B per flag line

typedef float f32x4 __attribute__((ext_vector_type(4)));
typedef __bf16 bf16x8 __attribute__((ext_vector_type(8)));

__device__ __forceinline__ unsigned short f2bf(float f) {
  union { float f; unsigned int i; } x; x.f = f;
  unsigned int r = x.i + 0x7fffu + ((x.i >> 16) & 1u);  // RNE
  return (unsigned short)(r >> 16);
}
__device__ __forceinline__ float sigm(float x) { return 1.0f / (1.0f + __expf(-x)); }
__device__ __forceinline__ float tanh_(float x) {
  float a = fabsf(x);
  float e = __expf(2.0f * a);
  float r = 1.0f - 2.0f / (e + 1.0f);
  return copysignf(r, x);
}
// convert 8 consecutive f32 -> bf16x8 (RNE)
__device__ __forceinline__ bf16x8 cvt8(const float* __restrict__ p) {
  f32x4 a = *(const f32x4*)(const void*)p;
  f32x4 b = *(const f32x4*)(const void*)(p + 4);
  union { bf16x8 v; unsigned short u[8]; } r;
  #pragma unroll
  for (int j = 0; j < 4; ++j) { r.u[j] = f2bf(a[j]); r.u[j + 4] = f2bf(b[j]); }
  return r.v;
}

// ws layout: [0, 16384) half-flags (128 x FLAG_STRIDE ints)
//            [16384, +131072) hbuf u16: [group 4][buf 2][slice 16][whalf 2][brow 16][hcol 16]
// Tag scheme: even-hcol u16s carry step tag in bf16 LSB. tau(t) = (t>>1)&1.
// Init: parity 0 = 0x0000 (== real h0, tag 0, VALID for t=0); parity 1 = 0x0001
// (tag 1, INVALID for t=1 which expects tag 0).
__global__ void lstm_init(int* __restrict__ ws) {
  int i = blockIdx.x * 256 + threadIdx.x;  // grid 144 -> 36864 ints
  if (i < 4096) ws[i] = 0;                 // flags
  int j = i - 4096;
  if (j >= 0 && j < 32768) {               // hbuf ints: group block = 8192 ints
    ws[4096 + j] = ((j & 8191) < 4096) ? 0 : 0x00010001;
  }
}

// 64 WGs x 128 threads. Group g = bid&3 owns batch rows 16g..16g+15 (independent
// recurrence). Member m = bid>>2 owns hidden cols 32m..32m+31; wave w owns 16.
// No __syncthreads in main loop; no read-side flag poll (tag-validated loads).
__global__ __launch_bounds__(128, 1) void lstm_persist(
    const float* __restrict__ X,     // [64, 2048, 256] f32
    const float* __restrict__ HID,   // [1, 512] f32 (passthrough)
    const float* __restrict__ Wi, const float* __restrict__ bi,
    const float* __restrict__ Wg, const float* __restrict__ bg,
    const float* __restrict__ Wo, const float* __restrict__ bo,
    const float* __restrict__ Wout, const float* __restrict__ bout,
    float* __restrict__ out,                  // f32: [64*256] + [512]
    unsigned short* __restrict__ hbuf,
    int* __restrict__ flags)
{
  extern __shared__ unsigned short ldsw[];  // 96*768 swizzled weights + 768 u16 scratch
  unsigned short* ldsh = ldsw + 96 * 768;   // per-wave [16 brow][24 pad] u16
  const int tid = threadIdx.x;
  const int b = blockIdx.x;
  const int g = b & 3;
  const int m = b >> 2;
  const int lane = tid & 63;
  const int wave = tid >> 6;
  const int q = lane >> 4;
  const int c = lane & 15;
  const int jb = m * 32;
  const int wcol = wave * 16;

  if (b == 0) {
    for (int i = tid; i < N_H; i += 128) out[N_B * N_IN + i] = HID[i];
  }

  // ---- stage weight slice into LDS (f32 -> bf16), transposed + swizzled ----
  for (int idx = tid; idx < 96 * 768; idx += 128) {
    int k = idx / 96, r = idx - k * 96;
    int g3 = r >> 5, cc = r & 31;
    const float* W = (g3 == 0) ? Wi : ((g3 == 1) ? Wg : Wo);
    unsigned short v = f2bf(W[k * N_H + jb + cc]);
    int byte = (r * 1536 + k * 2) ^ ((r & 7) << 4);  // XOR swizzle (G4)
    *(unsigned short*)((char*)ldsw + byte) = v;
  }
  __syncthreads();  // only block-wide barrier (weights read-only afterwards)

  auto ldb = [&](int gg, int kt) -> bf16x8 {
    int r = gg * 32 + wcol + c;
    int byte = (r * 1536 + kt * 64 + q * 16) ^ ((r & 7) << 4);
    return *(const bf16x8*)((const char*)ldsw + byte);
  };

  const float Bi = bi[jb + wcol + c];
  const float Bg = bg[jb + wcol + c];
  const float Bo = bo[jb + wcol + c];

  const float* xrow = X + (size_t)(g * 16 + c) * (T_LEN * N_IN);

  unsigned short* gh0 = hbuf + g * 16384;
  const int roff64 = (q >> 1) * 64 + c * 4 + (q & 1) * 2;   // reader u64 idx in slice
  const int swr = wave * 384;
  const int srb = wave * 384 + (lane >> 2) * 24 + (lane & 3) * 4;
  const int hflag = (g * 32 + m * 2 + wave) * FLAG_STRIDE;
  const int pflag = (g * 32 + (lane & 31)) * FLAG_STRIDE;
  const unsigned long long TAGM = 0x0000000100000001ull;  // LSB of u16[0],u16[2]

  #pragma unroll 1
  for (int t = 0; t < T_LEN; ++t) {
    // ---- (a) speculative h_t loads issued FIRST (validated later by tag) ----
    const unsigned long long* hb64 =
        (const unsigned long long*)(gh0 + (size_t)(t & 1) * 8192);
    unsigned long long hreg[32];
    #pragma unroll
    for (int kk = 0; kk < 16; ++kk) {
      hreg[2 * kk]     = __hip_atomic_load(hb64 + kk * 128 + roff64,
                                           __ATOMIC_RELAXED, __HIP_MEMORY_SCOPE_AGENT);
      hreg[2 * kk + 1] = __hip_atomic_load(hb64 + kk * 128 + roff64 + 1,
                                           __ATOMIC_RELAXED, __HIP_MEMORY_SCOPE_AGENT);
    }

    // ---- (b) x-part GEMM overlaps the load flight ----
    f32x4 ai = {0.f, 0.f, 0.f, 0.f};
    f32x4 ag = {0.f, 0.f, 0.f, 0.f};
    f32x4 ao = {0.f, 0.f, 0.f, 0.f};
    const float* xp = xrow + (size_t)t * N_IN + q * 8;
    #pragma unroll
    for (int kk = 0; kk < 8; ++kk) {
      bf16x8 a = cvt8(xp + kk * 32);
      ai = __builtin_amdgcn_mfma_f32_16x16x32_bf16(a, ldb(0, kk), ai, 0, 0, 0);
      ag = __builtin_amdgcn_mfma_f32_16x16x32_bf16(a, ldb(1, kk), ag, 0, 0, 0);
      ao = __builtin_amdgcn_mfma_f32_16x16x32_bf16(a, ldb(2, kk), ao, 0, 0, 0);
    }

    // ---- (c) validate tags; retry until producer data landed ----
    {
      const unsigned long long want = ((t >> 1) & 1) ? TAGM : 0ull;
      for (;;) {
        bool ok = true;
        #pragma unroll
        for (int i = 0; i < 32; ++i) ok &= ((hreg[i] & TAGM) == want);
        if (__all(ok)) break;
        #pragma unroll
        for (int kk = 0; kk < 16; ++kk) {
          hreg[2 * kk]     = __hip_atomic_load(hb64 + kk * 128 + roff64,
                                               __ATOMIC_RELAXED, __HIP_MEMORY_SCOPE_AGENT);
          hreg[2 * kk + 1] = __hip_atomic_load(hb64 + kk * 128 + roff64 + 1,
                                               __ATOMIC_RELAXED, __HIP_MEMORY_SCOPE_AGENT);
        }
      }
    }

    // ---- (d) h-part GEMM ----
    #pragma unroll
    for (int kk = 0; kk < 16; ++kk) {
      union { unsigned long long u[2]; bf16x8 v; } a;
      a.u[0] = hreg[2 * kk]; a.u[1] = hreg[2 * kk + 1];
      ai = __builtin_amdgcn_mfma_f32_16x16x32_bf16(a.v, ldb(0, kk + 8), ai, 0, 0, 0);
      ag = __builtin_amdgcn_mfma_f32_16x16x32_bf16(a.v, ldb(1, kk + 8), ag, 0, 0, 0);
      ao = __builtin_amdgcn_mfma_f32_16x16x32_bf16(a.v, ldb(2, kk + 8), ao, 0, 0, 0);
    }

    // ---- (e) write-safety poll (overlaps MFMA pipe; steady-state: 1 iteration) ----
    // flag >= t means that wave finished step t-1 (its reads of parity (t+1)&1 done)
    for (;;) {
      int v = __hip_atomic_load(&flags[pflag], __ATOMIC_RELAXED, __HIP_MEMORY_SCOPE_AGENT);
      if (__all(v >= t)) break;
    }

    // ---- (f) nonlinearity (tag even cols) -> scratch -> u64 store (relaxed) ----
    const unsigned short tau1 = (unsigned short)(((t + 1) >> 1) & 1);
    #pragma unroll
    for (int j = 0; j < 4; ++j) {
      float iv = sigm(ai[j] + Bi);
      float gv = tanh_(ag[j] + Bg);
      float ov = sigm(ao[j] + Bo);
      float h = ov * tanh_(iv * gv);
      unsigned short hv = f2bf(h);
      if ((c & 1) == 0) hv = (unsigned short)((hv & 0xFFFEu) | tau1);  // step tag
      ldsh[swr + (q * 4 + j) * 24 + c] = hv;  // D: col=lane&15, row=q*4+j (m89)
    }
    // ordering fix (r14 lesson): fence compiler + wait own LDS writes
    asm volatile("s_waitcnt lgkmcnt(0)" ::: "memory");
    {
      unsigned long long v64;
      __builtin_memcpy(&v64, (const void*)(ldsh + srb), 8);
      unsigned long long* hn =
          (unsigned long long*)(gh0 + (size_t)((t + 1) & 1) * 8192) + m * 128 + tid;
      __hip_atomic_store(hn, v64, __ATOMIC_RELAXED, __HIP_MEMORY_SCOPE_AGENT);
    }
    // RELAXED flag: consumers validate data via tags; flag only gates overwrite.
    // It is issued after MFMAs that data-depend on the h_t loads -> reads are
    // physically complete before the flag can be visible.
    if (lane == 0)
      __hip_atomic_store(&flags[hflag], t + 1,
                         __ATOMIC_RELAXED, __HIP_MEMORY_SCOPE_AGENT);
  }

  // ---- epilogue: out = h_T @ W_out + b_out ; h_T in parity 0, tag tau(2048)=0 ----
  if (wave == 0) {
    const unsigned long long* hb64 = (const unsigned long long*)gh0;
    unsigned long long he[32];
    for (;;) {
      #pragma unroll
      for (int kk = 0; kk < 16; ++kk) {
        he[2 * kk]     = __hip_atomic_load(hb64 + kk * 128 + roff64,
                                           __ATOMIC_RELAXED, __HIP_MEMORY_SCOPE_AGENT);
        he[2 * kk + 1] = __hip_atomic_load(hb64 + kk * 128 + roff64 + 1,
                                           __ATOMIC_RELAXED, __HIP_MEMORY_SCOPE_AGENT);
      }
      bool ok = true;
      #pragma unroll
      for (int i = 0; i < 32; ++i) ok &= ((he[i] & TAGM) == 0ull);
      if (__all(ok)) break;
    }
    f32x4 acc = {0.f, 0.f, 0.f, 0.f};
    #pragma unroll 4
    for (int kk = 0; kk < 16; ++kk) {
      union { unsigned long long u[2]; bf16x8 v; } a;
      a.u[0] = he[2 * kk]; a.u[1] = he[2 * kk + 1];
      union { bf16x8 v; unsigned short u[8]; } bb;
      #pragma unroll
      for (int j = 0; j < 8; ++j)
        bb.u[j] = f2bf(Wout[(size_t)(kk * 32 + q * 8 + j) * N_IN + m * 16 + c]);
      acc = __builtin_amdgcn_mfma_f32_16x16x32_bf16(a.v, bb.v, acc, 0, 0, 0);
    }
    const float Bb = bout[m * 16 + c];
    #pragma unroll
    for (int j = 0; j < 4; ++j) {
      int row = q * 4 + j;
      out[(g * 16 + row) * N_IN + m * 16 + c] = acc[j] + Bb;
    }
  }
}

extern "C" void kernel_launch(void* const* d_in, const int* in_sizes, int n_in,
                              void* d_out, int out_size, void* d_ws, size_t ws_size,
                              hipStream_t stream) {
  const float* X    = (const float*)d_in[0];
  const float* HID  = (const float*)d_in[1];
  const float* Wi   = (const float*)d_in[2];
  const float* bi   = (const float*)d_in[3];
  const float* Wg   = (const float*)d_in[4];
  const float* bg   = (const float*)d_in[5];
  const float* Wo   = (const float*)d_in[6];
  const float* bo   = (const float*)d_in[7];
  const float* Wout = (const float*)d_in[8];
  const float* bout = (const float*)d_in[9];

  int* flags = (int*)d_ws;
  unsigned short* hbuf = (unsigned short*)((char*)d_ws + 16384);

  lstm_init<<<dim3(144), dim3(256), 0, stream>>>((int*)d_ws);
  lstm_persist<<<dim3(64), dim3(128), 96 * 768 * 2 + 1536, stream>>>(
      X, HID, Wi, bi, Wg, bg, Wo, bo, Wout, bout,
      (float*)d_out, hbuf, flags);
}

// Round 17
// 6940.611 us; speedup vs baseline: 1.7276x; 1.2865x over previous
//
#include <hip/hip_runtime.h>
#include <hip/hip_bf16.h>

#define T_LEN 2048
#define N_IN 256
#define N_H 512
#define N_B 64

typedef float f32x4 __attribute__((ext_vector_type(4)));
typedef __bf16 bf16x8 __attribute__((ext_vector_type(8)));

__device__ __forceinline__ unsigned short f2bf(float f) {
  union { float f; unsigned int i; } x; x.f = f;
  unsigned int r = x.i + 0x7fffu + ((x.i >> 16) & 1u);  // RNE
  return (unsigned short)(r >> 16);
}
__device__ __forceinline__ float sigm(float x) { return 1.0f / (1.0f + __expf(-x)); }
__device__ __forceinline__ float tanh_(float x) {
  float a = fabsf(x);
  float e = __expf(2.0f * a);
  float r = 1.0f - 2.0f / (e + 1.0f);
  return copysignf(r, x);
}
// convert 8 consecutive f32 -> bf16x8 (RNE)
__device__ __forceinline__ bf16x8 cvt8(const float* __restrict__ p) {
  f32x4 a = *(const f32x4*)(const void*)p;
  f32x4 b = *(const f32x4*)(const void*)(p + 4);
  union { bf16x8 v; unsigned short u[8]; } r;
  #pragma unroll
  for (int j = 0; j < 4; ++j) { r.u[j] = f2bf(a[j]); r.u[j + 4] = f2bf(b[j]); }
  return r.v;
}

// ws layout: hbuf u16 only (NO FLAGS — tags inside the data are the sole sync):
//   [group 4][buf 4][slice 16][whalf 2][brow 16][hcol 16]
// group stride 32768 u16 (16384 ints), buf stride 8192 u16 (4096 ints).
// Tag scheme: even-hcol u16s carry tag in bf16 LSB. h_t lives in buf t&3 with
// tag tau(t) = (t>>2)&1. Init: buf 0 = 0x0000 (real h0, tag 0 = valid for t=0);
// bufs 1..3 = 0x0001 pattern (tag 1 = invalid for their first consumers t=1..3).
__global__ void lstm_init(int* __restrict__ ws) {
  int i = blockIdx.x * 256 + threadIdx.x;  // grid 256 -> 65536 ints = 256 KB
  ws[i] = ((i & 16383) < 4096) ? 0 : 0x00010001;
}

// 64 WGs x 128 threads. Group g = bid&3 owns batch rows 16g..16g+15 (independent
// recurrence). Member m = bid>>2 owns hidden cols 32m..32m+31; wave w owns 16.
// Zero barriers, zero flags in the main loop: tag-validated speculative loads
// provide both data freshness AND (transitively) overwrite safety with 4 bufs.
__global__ __launch_bounds__(128, 1) void lstm_persist(
    const float* __restrict__ X,     // [64, 2048, 256] f32
    const float* __restrict__ HID,   // [1, 512] f32 (passthrough)
    const float* __restrict__ Wi, const float* __restrict__ bi,
    const float* __restrict__ Wg, const float* __restrict__ bg,
    const float* __restrict__ Wo, const float* __restrict__ bo,
    const float* __restrict__ Wout, const float* __restrict__ bout,
    float* __restrict__ out,                  // f32: [64*256] + [512]
    unsigned short* __restrict__ hbuf)
{
  extern __shared__ unsigned short ldsw[];  // 96*768 swizzled weights + 768 u16 scratch
  unsigned short* ldsh = ldsw + 96 * 768;   // per-wave [16 brow][24 pad] u16
  const int tid = threadIdx.x;
  const int b = blockIdx.x;
  const int g = b & 3;
  const int m = b >> 2;
  const int lane = tid & 63;
  const int wave = tid >> 6;
  const int q = lane >> 4;
  const int c = lane & 15;
  const int jb = m * 32;
  const int wcol = wave * 16;

  if (b == 0) {
    for (int i = tid; i < N_H; i += 128) out[N_B * N_IN + i] = HID[i];
  }

  // ---- stage weight slice into LDS (f32 -> bf16), transposed + swizzled ----
  for (int idx = tid; idx < 96 * 768; idx += 128) {
    int k = idx / 96, r = idx - k * 96;
    int g3 = r >> 5, cc = r & 31;
    const float* W = (g3 == 0) ? Wi : ((g3 == 1) ? Wg : Wo);
    unsigned short v = f2bf(W[k * N_H + jb + cc]);
    int byte = (r * 1536 + k * 2) ^ ((r & 7) << 4);  // XOR swizzle (G4)
    *(unsigned short*)((char*)ldsw + byte) = v;
  }
  __syncthreads();  // only block-wide barrier (weights read-only afterwards)

  auto ldb = [&](int gg, int kt) -> bf16x8 {
    int r = gg * 32 + wcol + c;
    int byte = (r * 1536 + kt * 64 + q * 16) ^ ((r & 7) << 4);
    return *(const bf16x8*)((const char*)ldsw + byte);
  };

  const float Bi = bi[jb + wcol + c];
  const float Bg = bg[jb + wcol + c];
  const float Bo = bo[jb + wcol + c];

  const float* xrow = X + (size_t)(g * 16 + c) * (T_LEN * N_IN);

  unsigned short* gh0 = hbuf + g * 32768;                  // group base (u16)
  const int roff64 = (q >> 1) * 64 + c * 4 + (q & 1) * 2;  // reader u64 idx in slice
  const int swr = wave * 384;
  const int srb = wave * 384 + (lane >> 2) * 24 + (lane & 3) * 4;
  const unsigned long long TAGM = 0x0000000100000001ull;   // LSB of each dword

  #pragma unroll 1
  for (int t = 0; t < T_LEN; ++t) {
    // ---- (a) x-part GEMM first (phase-aligns the h loads with store landing) ----
    f32x4 ai = {0.f, 0.f, 0.f, 0.f};
    f32x4 ag = {0.f, 0.f, 0.f, 0.f};
    f32x4 ao = {0.f, 0.f, 0.f, 0.f};
    const float* xp = xrow + (size_t)t * N_IN + q * 8;
    #pragma unroll
    for (int kk = 0; kk < 8; ++kk) {
      bf16x8 a = cvt8(xp + kk * 32);
      ai = __builtin_amdgcn_mfma_f32_16x16x32_bf16(a, ldb(0, kk), ai, 0, 0, 0);
      ag = __builtin_amdgcn_mfma_f32_16x16x32_bf16(a, ldb(1, kk), ag, 0, 0, 0);
      ao = __builtin_amdgcn_mfma_f32_16x16x32_bf16(a, ldb(2, kk), ao, 0, 0, 0);
    }

    // ---- (b) tag-validated h_t loads from buf t&3 (the ONLY synchronization) ----
    const unsigned long long* hb64 =
        (const unsigned long long*)(gh0 + (size_t)(t & 3) * 8192);
    unsigned long long hreg[32];
    {
      const unsigned long long want = ((t >> 2) & 1) ? TAGM : 0ull;
      for (;;) {
        #pragma unroll
        for (int kk = 0; kk < 16; ++kk) {
          hreg[2 * kk]     = __hip_atomic_load(hb64 + kk * 128 + roff64,
                                               __ATOMIC_RELAXED, __HIP_MEMORY_SCOPE_AGENT);
          hreg[2 * kk + 1] = __hip_atomic_load(hb64 + kk * 128 + roff64 + 1,
                                               __ATOMIC_RELAXED, __HIP_MEMORY_SCOPE_AGENT);
        }
        bool ok = true;
        #pragma unroll
        for (int i = 0; i < 32; ++i) ok &= ((hreg[i] & TAGM) == want);
        if (__all(ok)) break;
      }
    }

    // ---- (c) h-part GEMM ----
    #pragma unroll
    for (int kk = 0; kk < 16; ++kk) {
      union { unsigned long long u[2]; bf16x8 v; } a;
      a.u[0] = hreg[2 * kk]; a.u[1] = hreg[2 * kk + 1];
      ai = __builtin_amdgcn_mfma_f32_16x16x32_bf16(a.v, ldb(0, kk + 8), ai, 0, 0, 0);
      ag = __builtin_amdgcn_mfma_f32_16x16x32_bf16(a.v, ldb(1, kk + 8), ag, 0, 0, 0);
      ao = __builtin_amdgcn_mfma_f32_16x16x32_bf16(a.v, ldb(2, kk + 8), ao, 0, 0, 0);
    }

    // ---- (d) nonlinearity (tag even cols) -> scratch -> u64 store to buf (t+1)&3 ----
    // Write-safety without flags: successful validation of h_t proves every wave
    // issued its h_t store => every wave finished its step t-1 reads => a fortiori
    // finished its step t-3 reads of buf (t+1)&3. Overwrite is safe.
    const unsigned short tau1 = (unsigned short)(((t + 1) >> 2) & 1);
    #pragma unroll
    for (int j = 0; j < 4; ++j) {
      float iv = sigm(ai[j] + Bi);
      float gv = tanh_(ag[j] + Bg);
      float ov = sigm(ao[j] + Bo);
      float h = ov * tanh_(iv * gv);
      unsigned short hv = f2bf(h);
      if ((c & 1) == 0) hv = (unsigned short)((hv & 0xFFFEu) | tau1);  // step tag
      ldsh[swr + (q * 4 + j) * 24 + c] = hv;  // D: col=lane&15, row=q*4+j (m89)
    }
    // ordering fix (r14 lesson): fence compiler + wait own LDS writes
    asm volatile("s_waitcnt lgkmcnt(0)" ::: "memory");
    {
      unsigned long long v64;
      __builtin_memcpy(&v64, (const void*)(ldsh + srb), 8);
      unsigned long long* hn =
          (unsigned long long*)(gh0 + (size_t)((t + 1) & 3) * 8192) + m * 128 + tid;
      __hip_atomic_store(hn, v64, __ATOMIC_RELAXED, __HIP_MEMORY_SCOPE_AGENT);
    }
  }

  // ---- epilogue: out = h_T @ W_out + b_out ; h_T in buf 2048&3 = 0, tag (2048>>2)&1 = 0 ----
  if (wave == 0) {
    const unsigned long long* hb64 = (const unsigned long long*)gh0;
    unsigned long long he[32];
    for (;;) {
      #pragma unroll
      for (int kk = 0; kk < 16; ++kk) {
        he[2 * kk]     = __hip_atomic_load(hb64 + kk * 128 + roff64,
                                           __ATOMIC_RELAXED, __HIP_MEMORY_SCOPE_AGENT);
        he[2 * kk + 1] = __hip_atomic_load(hb64 + kk * 128 + roff64 + 1,
                                           __ATOMIC_RELAXED, __HIP_MEMORY_SCOPE_AGENT);
      }
      bool ok = true;
      #pragma unroll
      for (int i = 0; i < 32; ++i) ok &= ((he[i] & TAGM) == 0ull);
      if (__all(ok)) break;
    }
    f32x4 acc = {0.f, 0.f, 0.f, 0.f};
    #pragma unroll 4
    for (int kk = 0; kk < 16; ++kk) {
      union { unsigned long long u[2]; bf16x8 v; } a;
      a.u[0] = he[2 * kk]; a.u[1] = he[2 * kk + 1];
      union { bf16x8 v; unsigned short u[8]; } bb;
      #pragma unroll
      for (int j = 0; j < 8; ++j)
        bb.u[j] = f2bf(Wout[(size_t)(kk * 32 + q * 8 + j) * N_IN + m * 16 + c]);
      acc = __builtin_amdgcn_mfma_f32_16x16x32_bf16(a.v, bb.v, acc, 0, 0, 0);
    }
    const float Bb = bout[m * 16 + c];
    #pragma unroll
    for (int j = 0; j < 4; ++j) {
      int row = q * 4 + j;
      out[(g * 16 + row) * N_IN + m * 16 + c] = acc[j] + Bb;
    }
  }
}

extern "C" void kernel_launch(void* const* d_in, const int* in_sizes, int n_in,
                              void* d_out, int out_size, void* d_ws, size_t ws_size,
                              hipStream_t stream) {
  const float* X    = (const float*)d_in[0];
  const float* HID  = (const float*)d_in[1];
  const float* Wi   = (const float*)d_in[2];
  const float* bi   = (const float*)d_in[3];
  const float* Wg   = (const float*)d_in[4];
  const float* bg   = (const float*)d_in[5];
  const float* Wo   = (const float*)d_in[6];
  const float* bo   = (const float*)d_in[7];
  const float* Wout = (const float*)d_in[8];
  const float* bout = (const float*)d_in[9];

  unsigned short* hbuf = (unsigned short*)d_ws;  // 256 KB

  lstm_init<<<dim3(256), dim3(256), 0, stream>>>((int*)d_ws);
  lstm_persist<<<dim3(64), dim3(128), 96 * 768 * 2 + 1536, stream>>>(
      X, HID, Wi, bi, Wg, bg, Wo, bo, Wout, bout,
      (float*)d_out, hbuf);
}